// Round 5
// baseline (477.405 us; speedup 1.0000x reference)
//
#include <hip/hip_runtime.h>
#include <math.h>

// B=512, IN_CORES=12, N_PRIM=12, N_PAR=10, RFPC=4, RF=64, CAP=256
// out = concat( sigmoid MLP output (512,3072) f32 , x_sum (512,2560) f32 )

#define BATCH 512
#define OUT0_SZ (512*3072)

typedef __attribute__((ext_vector_type(8))) short short8;   // 8 x bf16
typedef __attribute__((ext_vector_type(4))) float f32x4;

__device__ inline unsigned short f2bf(float f) {
    union { float f; unsigned u; } v; v.f = f;
    unsigned r = v.u + 0x7fffu + ((v.u >> 16) & 1u);   // RNE
    return (unsigned short)(r >> 16);
}

// async global->LDS, 16 bytes per lane
#define GLD16(g, l) __builtin_amdgcn_global_load_lds( \
    (const __attribute__((address_space(1))) unsigned int*)(g), \
    (__attribute__((address_space(3))) unsigned int*)(l), 16, 0, 0)

// ---------------------------------------------------------------------------
// Fused capsule path (fp32, exact): caps1 + caps2 + skip + norm/argmax/mask.
// One block per batch row. x_prim lives only in LDS. x_sum values stay in
// registers (vk[10]) for the mask write. rsh broadcast is wave-local
// (reader (l,m) reads writer (l,mm), same wave) -> no barrier needed there.
// ---------------------------------------------------------------------------
__global__ __launch_bounds__(256) void caps_fused(
    const float* __restrict__ x,
    const float* __restrict__ C1, const float* __restrict__ W1, const float* __restrict__ b1,
    const float* __restrict__ Cs, const float* __restrict__ C2,
    const float* __restrict__ W2, const float* __restrict__ b2,
    float* __restrict__ xsum, unsigned short* __restrict__ xrec)
{
    __shared__ float xb[3072];
    __shared__ float xps[3072];
    __shared__ float rsh[256];
    __shared__ float part[40];
    __shared__ int act_sh;

    int b = blockIdx.x;
    int tid = threadIdx.x;
    int l = tid >> 6, m = tid & 63;

    // stage x row
    {
        const float4* g = (const float4*)(x + (size_t)b * 3072);
        #pragma unroll
        for (int p = 0; p < 3; ++p)
            ((float4*)xb)[tid + p * 256] = g[tid + p * 256];
    }
    __syncthreads();

    // ---- phase A: primary capsules -> xps (LDS only) ----
    for (int k = 0; k < 12; ++k) {
        int cbase = k * 4 + l;
        float r = 0.f;
        #pragma unroll 8
        for (int ij = 0; ij < 48; ++ij)
            r += C1[ij * 48 + cbase] * xb[ij * 64 + m];
        rsh[tid] = r;                       // wave-local broadcast buffer
        const float* Wkl = W1 + (size_t)(k * 4 + l) * 4096;
        float acc = b1[(k * 4 + l) * 64 + m];
        const float* rp = &rsh[l * 64];
        #pragma unroll 8
        for (int mm = 0; mm < 64; ++mm)
            acc += rp[mm] * Wkl[mm * 64 + m];
        xps[k * 256 + tid] = fmaxf(acc, 0.f);
    }
    __syncthreads();                         // xps cross-wave handoff

    // ---- phase B: parent capsules + skip; keep values in regs ----
    float vk[10];
    for (int k = 0; k < 10; ++k) {
        int cbase = k * 4 + l;
        float r = 0.f, sk = 0.f;
        #pragma unroll 8
        for (int ij = 0; ij < 48; ++ij) {
            float xv = xps[ij * 64 + m];
            r  += C2[ij * 40 + cbase] * xv;
            sk += Cs[ij * 40 + cbase] * xv;
        }
        rsh[tid] = r;
        const float* Wkl = W2 + (size_t)(k * 4 + l) * 4096;
        float acc = b2[(k * 4 + l) * 64 + m];
        const float* rp = &rsh[l * 64];
        #pragma unroll 8
        for (int mm = 0; mm < 64; ++mm)
            acc += rp[mm] * Wkl[mm * 64 + m];
        float v = sk + fmaxf(acc, 0.f);
        vk[k] = v;
        xsum[(size_t)b * 2560 + k * 256 + tid] = v;
        // wave-level norm^2 partial
        float s = v * v;
        #pragma unroll
        for (int off = 1; off <= 32; off <<= 1)
            s += __shfl_xor(s, off);
        if (m == 0) part[k * 4 + l] = s;
    }
    __syncthreads();

    if (tid == 0) {
        int best = 0; float bn = -1.f;
        #pragma unroll
        for (int k = 0; k < 10; ++k) {
            float s = part[k * 4] + part[k * 4 + 1] + part[k * 4 + 2] + part[k * 4 + 3];
            if (s > bn) { bn = s; best = k; }
        }
        act_sh = best;
    }
    __syncthreads();
    int act = act_sh;
    unsigned short* xr = xrec + (size_t)b * 2560;
    #pragma unroll
    for (int k = 0; k < 10; ++k)
        xr[k * 256 + tid] = (k == act) ? f2bf(vk[k]) : (unsigned short)0;
}

// ---------------------------------------------------------------------------
// Fused weight convert+transpose for all 3 layers, one dispatch.
// W[Kr][Nr] f32 -> Wt[Np][Kp] bf16 zero-padded, 64x64 LDS tiles (stride 65).
// Flattened grid: L1 40x80=3200, L2 80x64=5120, L3 64x48=3072 tiles.
// ---------------------------------------------------------------------------
__global__ __launch_bounds__(256) void convT_all(
    const float* __restrict__ Wr1, unsigned short* __restrict__ Wt1,
    const float* __restrict__ Wr2, unsigned short* __restrict__ Wt2,
    const float* __restrict__ Wr3, unsigned short* __restrict__ Wt3)
{
    __shared__ float t[64 * 65];
    int bid = blockIdx.x;
    const float* W; unsigned short* Wt;
    int Kr, Nr, Kp, ktiles, rem;
    if (bid < 3200)      { W = Wr1; Wt = Wt1; Kr = 2560; Nr = 5000; Kp = 2560; ktiles = 40; rem = bid; }
    else if (bid < 8320) { W = Wr2; Wt = Wt2; Kr = 5000; Nr = 4000; Kp = 5120; ktiles = 80; rem = bid - 3200; }
    else                 { W = Wr3; Wt = Wt3; Kr = 4000; Nr = 3072; Kp = 4096; ktiles = 64; rem = bid - 8320; }
    int k0 = (rem % ktiles) * 64;
    int n0 = (rem / ktiles) * 64;
    int tid = threadIdx.x;

    // load phase: float4 global -> scalar LDS (stride 65 = 2-way banking, free)
    {
        int kr = tid >> 4;
        int nc = (tid & 15) * 4;
        #pragma unroll
        for (int p = 0; p < 4; ++p) {
            int k = k0 + kr + p * 16;
            float4 v = make_float4(0.f, 0.f, 0.f, 0.f);
            if (k < Kr) {
                if (n0 + nc + 3 < Nr) {
                    v = *(const float4*)&W[(size_t)k * Nr + n0 + nc];
                } else {
                    float tmp[4] = {0.f, 0.f, 0.f, 0.f};
                    #pragma unroll
                    for (int j = 0; j < 4; ++j)
                        if (n0 + nc + j < Nr) tmp[j] = W[(size_t)k * Nr + n0 + nc + j];
                    v = make_float4(tmp[0], tmp[1], tmp[2], tmp[3]);
                }
            }
            float* row = &t[(kr + p * 16) * 65 + nc];
            row[0] = v.x; row[1] = v.y; row[2] = v.z; row[3] = v.w;
        }
    }
    __syncthreads();

    // store phase: 16 strided LDS reads (2-way), pack bf16, two 16B stores
    {
        int nr = tid >> 2;
        int kc = (tid & 3) * 16;
        unsigned int u[8];
        #pragma unroll
        for (int j = 0; j < 8; ++j) {
            float v0 = t[(kc + 2 * j)     * 65 + nr];
            float v1 = t[(kc + 2 * j + 1) * 65 + nr];
            u[j] = (unsigned int)f2bf(v0) | ((unsigned int)f2bf(v1) << 16);
        }
        unsigned int* dst = (unsigned int*)&Wt[(size_t)(n0 + nr) * Kp + k0 + kc];
        *(uint4*)(dst)     = make_uint4(u[0], u[1], u[2], u[3]);
        *(uint4*)(dst + 4) = make_uint4(u[4], u[5], u[6], u[7]);
    }
}

// ---------------------------------------------------------------------------
// Split-K MFMA GEMM (m97 structure): P[z] = A[M,Kp] @ Bt[Np,Kp]^T slice
// 128x128 tile, BK=32, 4 waves (2x2), 4x4 frags of 16x16x32.
// ---------------------------------------------------------------------------
#define SPLITK 4
__global__ __launch_bounds__(256) void gemm_splitk(
    const unsigned short* __restrict__ A, int ldA,
    const unsigned short* __restrict__ Bt, int ldB,
    float* __restrict__ P, int Np, int kper)
{
    __shared__ __align__(16) unsigned short As[128 * 32];
    __shared__ __align__(16) unsigned short Bs[128 * 32];

    int tid = threadIdx.x;
    int bn = blockIdx.x * 128;
    int bm = blockIdx.y * 128;
    int kz = blockIdx.z * kper;

    int w = tid >> 6, lane = tid & 63;
    int wm = (w >> 1) * 64, wn = (w & 1) * 64;
    int q = lane >> 4, r16 = lane & 15;

    int srow = tid >> 2, skq = tid & 3;

    f32x4 acc[4][4];
    #pragma unroll
    for (int i = 0; i < 4; ++i)
        #pragma unroll
        for (int j = 0; j < 4; ++j) acc[i][j] = (f32x4)0.f;

    for (int kk = 0; kk < kper; kk += 32) {
        int k0 = kz + kk;
        const unsigned short* ga = A + (size_t)(bm + srow) * ldA + k0 + skq * 8;
        GLD16(ga, &As[tid * 8]);
        GLD16(ga + (size_t)64 * ldA, &As[(tid + 256) * 8]);
        const unsigned short* gb = Bt + (size_t)(bn + srow) * ldB + k0 + skq * 8;
        GLD16(gb, &Bs[tid * 8]);
        GLD16(gb + (size_t)64 * ldB, &Bs[(tid + 256) * 8]);
        __syncthreads();

        short8 a[4], b[4];
        #pragma unroll
        for (int mt = 0; mt < 4; ++mt)
            a[mt] = *(const short8*)&As[(wm + mt * 16 + r16) * 32 + q * 8];
        #pragma unroll
        for (int nt = 0; nt < 4; ++nt)
            b[nt] = *(const short8*)&Bs[(wn + nt * 16 + r16) * 32 + q * 8];
        #pragma unroll
        for (int mt = 0; mt < 4; ++mt)
            #pragma unroll
            for (int nt = 0; nt < 4; ++nt)
                acc[mt][nt] = __builtin_amdgcn_mfma_f32_16x16x32_bf16(a[mt], b[nt], acc[mt][nt], 0, 0, 0);
        __syncthreads();
    }

    float* Pz = P + (size_t)blockIdx.z * 512 * Np;
    #pragma unroll
    for (int mt = 0; mt < 4; ++mt) {
        #pragma unroll
        for (int nt = 0; nt < 4; ++nt) {
            int cn = bn + wn + nt * 16 + r16;
            #pragma unroll
            for (int reg = 0; reg < 4; ++reg) {
                int cm = bm + wm + mt * 16 + q * 4 + reg;
                Pz[(size_t)cm * Np + cn] = acc[mt][nt][reg];
            }
        }
    }
}

// ---------------------------------------------------------------------------
// Combine split-K partials + bias + act.
// MODE 0: relu -> bf16. MODE 1: sigmoid -> f32.
// ---------------------------------------------------------------------------
template<int MODE>
__global__ __launch_bounds__(256) void combine_kernel(
    const float* __restrict__ P, const float* __restrict__ bias,
    void* __restrict__ out, int Np, int N_real)
{
    int gid = blockIdx.x * 256 + threadIdx.x;
    int n0 = (gid * 4) % Np;
    int m  = (gid * 4) / Np;
    size_t MN = (size_t)512 * Np;
    const float* p = P + (size_t)m * Np + n0;
    f32x4 s = *(const f32x4*)p;
    s += *(const f32x4*)(p + MN);
    s += *(const f32x4*)(p + 2 * MN);
    s += *(const f32x4*)(p + 3 * MN);
    f32x4 bv = (n0 < N_real) ? *(const f32x4*)(bias + n0) : (f32x4)0.f;
    s += bv;
    if (MODE == 0) {
        unsigned int lo = (unsigned int)f2bf(fmaxf(s[0], 0.f)) | ((unsigned int)f2bf(fmaxf(s[1], 0.f)) << 16);
        unsigned int hi = (unsigned int)f2bf(fmaxf(s[2], 0.f)) | ((unsigned int)f2bf(fmaxf(s[3], 0.f)) << 16);
        *(uint2*)((unsigned short*)out + (size_t)m * Np + n0) = make_uint2(lo, hi);
    } else {
        f32x4 v;
        v[0] = 1.f / (1.f + expf(-s[0]));
        v[1] = 1.f / (1.f + expf(-s[1]));
        v[2] = 1.f / (1.f + expf(-s[2]));
        v[3] = 1.f / (1.f + expf(-s[3]));
        *(f32x4*)((float*)out + (size_t)m * Np + n0) = v;
    }
}

extern "C" void kernel_launch(void* const* d_in, const int* in_sizes, int n_in,
                              void* d_out, int out_size, void* d_ws, size_t ws_size,
                              hipStream_t stream) {
    const float* x   = (const float*)d_in[0];
    const float* C1  = (const float*)d_in[1];
    const float* W1  = (const float*)d_in[2];
    const float* b1  = (const float*)d_in[3];
    const float* Cs  = (const float*)d_in[4];
    const float* C2  = (const float*)d_in[5];
    const float* W2  = (const float*)d_in[6];
    const float* b2  = (const float*)d_in[7];
    const float* Wr1 = (const float*)d_in[8];
    const float* br1 = (const float*)d_in[9];
    const float* Wr2 = (const float*)d_in[10];
    const float* br2 = (const float*)d_in[11];
    const float* Wr3 = (const float*)d_in[12];
    const float* br3 = (const float*)d_in[13];

    float* out = (float*)d_out;
    float* out0     = out;              // (512,3072) f32 sigmoid output
    float* xsum_out = out + OUT0_SZ;    // (512,2560) f32 x_sum (exact)

    // workspace layout (bytes)
    char* base = (char*)d_ws;
    unsigned short* xrec = (unsigned short*)(base);              //   2,621,440
    unsigned short* h1   = (unsigned short*)(base +   2621440);  //   5,242,880
    unsigned short* h2   = (unsigned short*)(base +   7864320);  //   4,194,304
    unsigned short* Wt1  = (unsigned short*)(base +  12058624);  //  26,214,400
    unsigned short* Wt2  = (unsigned short*)(base +  38273024);  //  41,943,040
    unsigned short* Wt3  = (unsigned short*)(base +  80216064);  //  25,165,824
    float*          Pbuf = (float*)(base + 105381888);           //  41,943,040
    // total: 147,324,928 B

    // weight convert (all 3 layers, one dispatch)
    convT_all<<<11392, 256, 0, stream>>>(Wr1, Wt1, Wr2, Wt2, Wr3, Wt3);

    // fused capsule path (exact fp32 -> output 1 + bf16 x_recon)
    caps_fused<<<BATCH, 256, 0, stream>>>(x, C1, W1, b1, Cs, C2, W2, b2, xsum_out, xrec);

    // --- layer 1: (512,2560) @ (2560,5000) -> h1 (512,5120 bf16) ---
    gemm_splitk<<<dim3(5120 / 128, 4, SPLITK), 256, 0, stream>>>(xrec, 2560, Wt1, 2560, Pbuf, 5120, 2560 / SPLITK);
    combine_kernel<0><<<512 * 5120 / 1024, 256, 0, stream>>>(Pbuf, br1, h1, 5120, 5000);

    // --- layer 2: (512,5120) @ (5120,4000) -> h2 (512,4096 bf16) ---
    gemm_splitk<<<dim3(4096 / 128, 4, SPLITK), 256, 0, stream>>>(h1, 5120, Wt2, 5120, Pbuf, 4096, 5120 / SPLITK);
    combine_kernel<0><<<512 * 4096 / 1024, 256, 0, stream>>>(Pbuf, br2, h2, 4096, 4000);

    // --- layer 3: (512,4096) @ (4096,3072) -> out0 (512,3072 f32, sigmoid) ---
    gemm_splitk<<<dim3(3072 / 128, 4, SPLITK), 256, 0, stream>>>(h2, 4096, Wt3, 4096, Pbuf, 3072, 4096 / SPLITK);
    combine_kernel<1><<<512 * 3072 / 1024, 256, 0, stream>>>(Pbuf, br3, out0, 3072, 3072);
}

// Round 6
// 410.013 us; speedup vs baseline: 1.1644x; 1.1644x over previous
//
#include <hip/hip_runtime.h>
#include <math.h>

// B=512, IN_CORES=12, N_PRIM=12, N_PAR=10, RFPC=4, RF=64, CAP=256
// out = concat( sigmoid MLP output (512,3072) f32 , x_sum (512,2560) f32 )
// Key structural fact: C1/C_skip/C2 are Bernoulli 0/1 -> routing einsum is
// sparse sum-pooling over ~20% of 48 input blocks.

#define BATCH 512
#define OUT0_SZ (512*3072)

typedef __attribute__((ext_vector_type(8))) short short8;   // 8 x bf16
typedef __attribute__((ext_vector_type(4))) float f32x4;

__device__ inline unsigned short f2bf(float f) {
    union { float f; unsigned u; } v; v.f = f;
    unsigned r = v.u + 0x7fffu + ((v.u >> 16) & 1u);   // RNE
    return (unsigned short)(r >> 16);
}
__device__ inline float bf2f(unsigned int hi16) {       // low 16 bits = bf16
    union { unsigned u; float f; } v; v.u = hi16 << 16; return v.f;
}

// async global->LDS, 16 bytes per lane
#define GLD16(g, l) __builtin_amdgcn_global_load_lds( \
    (const __attribute__((address_space(1))) unsigned int*)(g), \
    (__attribute__((address_space(3))) unsigned int*)(l), 16, 0, 0)

// ---------------------------------------------------------------------------
// Prep: MLP weight convert+transpose (f32 [K][N] -> bf16 [N][K], padded)
// + capsule weight transpose W1/W2 (per-kl 64x64, [m][n] -> [n][m] bf16).
// 64x64 LDS tiles, stride 65. One dispatch, flattened grid.
//   L1 40x80=3200 | L2 80x64=5120 | L3 64x48=3072 | W1t 48 | W2t 40
// ---------------------------------------------------------------------------
__global__ __launch_bounds__(256) void convT_all(
    const float* __restrict__ Wr1, unsigned short* __restrict__ Wt1,
    const float* __restrict__ Wr2, unsigned short* __restrict__ Wt2,
    const float* __restrict__ Wr3, unsigned short* __restrict__ Wt3,
    const float* __restrict__ W1,  unsigned short* __restrict__ W1t,
    const float* __restrict__ W2,  unsigned short* __restrict__ W2t)
{
    __shared__ float t[64 * 65];
    int bid = blockIdx.x;
    const float* W; unsigned short* Wt;
    int Kr, Nr, Kp, ktiles, rem;
    if (bid < 3200)       { W = Wr1; Wt = Wt1; Kr = 2560; Nr = 5000; Kp = 2560; ktiles = 40; rem = bid; }
    else if (bid < 8320)  { W = Wr2; Wt = Wt2; Kr = 5000; Nr = 4000; Kp = 5120; ktiles = 80; rem = bid - 3200; }
    else if (bid < 11392) { W = Wr3; Wt = Wt3; Kr = 4000; Nr = 3072; Kp = 4096; ktiles = 64; rem = bid - 8320; }
    else if (bid < 11440) { int kl = bid - 11392; W = W1 + (size_t)kl * 4096; Wt = W1t + (size_t)kl * 4096;
                            Kr = 64; Nr = 64; Kp = 64; ktiles = 1; rem = 0; }
    else                  { int kl = bid - 11440; W = W2 + (size_t)kl * 4096; Wt = W2t + (size_t)kl * 4096;
                            Kr = 64; Nr = 64; Kp = 64; ktiles = 1; rem = 0; }
    int k0 = (rem % ktiles) * 64;
    int n0 = (rem / ktiles) * 64;
    int tid = threadIdx.x;

    // load: float4 global -> scalar LDS (stride 65 -> 2-way banking, free)
    {
        int kr = tid >> 4;
        int nc = (tid & 15) * 4;
        #pragma unroll
        for (int p = 0; p < 4; ++p) {
            int k = k0 + kr + p * 16;
            float4 v = make_float4(0.f, 0.f, 0.f, 0.f);
            if (k < Kr) {
                if (n0 + nc + 3 < Nr) {
                    v = *(const float4*)&W[(size_t)k * Nr + n0 + nc];
                } else {
                    float tmp[4] = {0.f, 0.f, 0.f, 0.f};
                    #pragma unroll
                    for (int j = 0; j < 4; ++j)
                        if (n0 + nc + j < Nr) tmp[j] = W[(size_t)k * Nr + n0 + nc + j];
                    v = make_float4(tmp[0], tmp[1], tmp[2], tmp[3]);
                }
            }
            float* row = &t[(kr + p * 16) * 65 + nc];
            row[0] = v.x; row[1] = v.y; row[2] = v.z; row[3] = v.w;
        }
    }
    __syncthreads();
    // store: strided LDS reads (2-way), pack bf16, two 16B stores
    {
        int nr = tid >> 2;
        int kc = (tid & 3) * 16;
        unsigned int u[8];
        #pragma unroll
        for (int j = 0; j < 8; ++j) {
            float v0 = t[(kc + 2 * j)     * 65 + nr];
            float v1 = t[(kc + 2 * j + 1) * 65 + nr];
            u[j] = (unsigned int)f2bf(v0) | ((unsigned int)f2bf(v1) << 16);
        }
        unsigned int* dst = (unsigned int*)&Wt[(size_t)(n0 + nr) * Kp + k0 + kc];
        *(uint4*)(dst)     = make_uint4(u[0], u[1], u[2], u[3]);
        *(uint4*)(dst + 4) = make_uint4(u[4], u[5], u[6], u[7]);
    }
}

// ---------------------------------------------------------------------------
// Capsule layer 1 as pooled MFMA GEMM. Grid (48 kl, 4 m-tiles), 256 thr.
// A-tile (128x64): routed = sum over active ij of x[:, ij*64 : +64] (fp32
// reads, reg accumulate, pack bf16 -> LDS). B-tile: W1t[kl] (64x64 bf16).
// One BK=64 MFMA pass (2 k-steps). Epilogue: relu(acc + b1) -> xp bf16.
// ---------------------------------------------------------------------------
__global__ __launch_bounds__(256) void caps_gemm1(
    const float* __restrict__ x, const float* __restrict__ C1,
    const unsigned short* __restrict__ W1t, const float* __restrict__ b1,
    unsigned short* __restrict__ xp)
{
    __shared__ __align__(16) unsigned short As[128 * 72];
    __shared__ __align__(16) unsigned short Bs[64 * 72];
    __shared__ float Csh[48];
    int kl = blockIdx.x;
    int bm = blockIdx.y * 128;
    int tid = threadIdx.x;
    int w = tid >> 6, lane = tid & 63, q = lane >> 4, r16 = lane & 15;
    int wm = (w >> 1) * 64, wn = (w & 1) * 32;

    if (tid < 48) Csh[tid] = C1[tid * 48 + kl];
    {   // stage B = W1t[kl], 64x64 bf16, padded stride 72
        const uint4* src = (const uint4*)(W1t + (size_t)kl * 4096);
        #pragma unroll
        for (int p = 0; p < 2; ++p) {
            int c = tid + p * 256;
            int row = c >> 3, cq = c & 7;
            *(uint4*)&Bs[row * 72 + cq * 8] = src[c];
        }
    }
    __syncthreads();

    // A-pool: thread -> (row = tid>>1, 32-col half)
    int arow = tid >> 1, ah = (tid & 1) * 32;
    float accp[32];
    #pragma unroll
    for (int i = 0; i < 32; ++i) accp[i] = 0.f;
    const float* xrow = x + (size_t)(bm + arow) * 3072 + ah;
    for (int ij = 0; ij < 48; ++ij) {
        float c = Csh[ij];
        if (c != 0.f) {
            const float4* p4 = (const float4*)(xrow + ij * 64);
            #pragma unroll
            for (int cc = 0; cc < 8; ++cc) {
                float4 v = p4[cc];
                accp[cc * 4 + 0] = fmaf(c, v.x, accp[cc * 4 + 0]);
                accp[cc * 4 + 1] = fmaf(c, v.y, accp[cc * 4 + 1]);
                accp[cc * 4 + 2] = fmaf(c, v.z, accp[cc * 4 + 2]);
                accp[cc * 4 + 3] = fmaf(c, v.w, accp[cc * 4 + 3]);
            }
        }
    }
    {   // pack -> As
        unsigned short* dst = &As[arow * 72 + ah];
        #pragma unroll
        for (int cc = 0; cc < 4; ++cc) {
            unsigned int u[4];
            #pragma unroll
            for (int j = 0; j < 4; ++j)
                u[j] = (unsigned int)f2bf(accp[cc * 8 + 2 * j]) |
                       ((unsigned int)f2bf(accp[cc * 8 + 2 * j + 1]) << 16);
            *(uint4*)&dst[cc * 8] = make_uint4(u[0], u[1], u[2], u[3]);
        }
    }
    __syncthreads();

    f32x4 acc[4][2];
    #pragma unroll
    for (int i = 0; i < 4; ++i)
        #pragma unroll
        for (int j = 0; j < 2; ++j) acc[i][j] = (f32x4)0.f;
    #pragma unroll
    for (int ks = 0; ks < 2; ++ks) {
        short8 a[4], b[2];
        #pragma unroll
        for (int mt = 0; mt < 4; ++mt)
            a[mt] = *(const short8*)&As[(wm + mt * 16 + r16) * 72 + ks * 32 + q * 8];
        #pragma unroll
        for (int nt = 0; nt < 2; ++nt)
            b[nt] = *(const short8*)&Bs[(wn + nt * 16 + r16) * 72 + ks * 32 + q * 8];
        #pragma unroll
        for (int mt = 0; mt < 4; ++mt)
            #pragma unroll
            for (int nt = 0; nt < 2; ++nt)
                acc[mt][nt] = __builtin_amdgcn_mfma_f32_16x16x32_bf16(a[mt], b[nt], acc[mt][nt], 0, 0, 0);
    }

    #pragma unroll
    for (int mt = 0; mt < 4; ++mt) {
        #pragma unroll
        for (int nt = 0; nt < 2; ++nt) {
            int n = wn + nt * 16 + r16;
            float bv = b1[kl * 64 + n];
            #pragma unroll
            for (int reg = 0; reg < 4; ++reg) {
                int row = bm + wm + mt * 16 + q * 4 + reg;
                xp[(size_t)row * 3072 + kl * 64 + n] = f2bf(fmaxf(acc[mt][nt][reg] + bv, 0.f));
            }
        }
    }
}

// ---------------------------------------------------------------------------
// Capsule layer 2 + skip + norms. Grid (40 kl, 4 m-tiles), 256 thr.
// A-pool (C2) and skip-pool (C_skip) from xp bf16 in one pass over active ij.
// skip tile kept in LDS f32. Epilogue: x_sum = skip + relu(acc+b2) -> f32 out,
// per-row norm^2 32-col partials -> part8[row][kl*2+half] (no atomics).
// ---------------------------------------------------------------------------
__global__ __launch_bounds__(256) void caps_gemm2(
    const unsigned short* __restrict__ xp, const float* __restrict__ Cs,
    const float* __restrict__ C2, const unsigned short* __restrict__ W2t,
    const float* __restrict__ b2, float* __restrict__ xsum,
    float* __restrict__ part8)
{
    __shared__ __align__(16) unsigned short As[128 * 72];
    __shared__ __align__(16) unsigned short Bs[64 * 72];
    __shared__ __align__(16) float Sk[128 * 68];
    __shared__ float C2sh[48], Cssh[48];
    int kl = blockIdx.x;
    int bm = blockIdx.y * 128;
    int tid = threadIdx.x;
    int w = tid >> 6, lane = tid & 63, q = lane >> 4, r16 = lane & 15;
    int wm = (w >> 1) * 64, wn = (w & 1) * 32;
    int half = w & 1;

    if (tid < 48) { C2sh[tid] = C2[tid * 40 + kl]; Cssh[tid] = Cs[tid * 40 + kl]; }
    {
        const uint4* src = (const uint4*)(W2t + (size_t)kl * 4096);
        #pragma unroll
        for (int p = 0; p < 2; ++p) {
            int c = tid + p * 256;
            int row = c >> 3, cq = c & 7;
            *(uint4*)&Bs[row * 72 + cq * 8] = src[c];
        }
    }
    __syncthreads();

    int arow = tid >> 1, ah = (tid & 1) * 32;
    float accp[32], skp[32];
    #pragma unroll
    for (int i = 0; i < 32; ++i) { accp[i] = 0.f; skp[i] = 0.f; }
    const unsigned short* xprow = xp + (size_t)(bm + arow) * 3072 + ah;
    for (int ij = 0; ij < 48; ++ij) {
        float c2 = C2sh[ij], cs = Cssh[ij];
        if (c2 != 0.f || cs != 0.f) {
            const uint4* p4 = (const uint4*)(xprow + ij * 64);
            #pragma unroll
            for (int cc = 0; cc < 4; ++cc) {
                uint4 v = p4[cc];
                unsigned int uu[4] = {v.x, v.y, v.z, v.w};
                #pragma unroll
                for (int j = 0; j < 4; ++j) {
                    float lo = bf2f(uu[j] & 0xffffu);
                    float hi = bf2f(uu[j] >> 16);
                    int idx = cc * 8 + 2 * j;
                    accp[idx]     = fmaf(c2, lo, accp[idx]);
                    accp[idx + 1] = fmaf(c2, hi, accp[idx + 1]);
                    skp[idx]      = fmaf(cs, lo, skp[idx]);
                    skp[idx + 1]  = fmaf(cs, hi, skp[idx + 1]);
                }
            }
        }
    }
    {   // routed -> As (bf16), skip -> Sk (f32)
        unsigned short* dst = &As[arow * 72 + ah];
        #pragma unroll
        for (int cc = 0; cc < 4; ++cc) {
            unsigned int u[4];
            #pragma unroll
            for (int j = 0; j < 4; ++j)
                u[j] = (unsigned int)f2bf(accp[cc * 8 + 2 * j]) |
                       ((unsigned int)f2bf(accp[cc * 8 + 2 * j + 1]) << 16);
            *(uint4*)&dst[cc * 8] = make_uint4(u[0], u[1], u[2], u[3]);
        }
        float* sdst = &Sk[arow * 68 + ah];
        #pragma unroll
        for (int cc = 0; cc < 8; ++cc)
            *(float4*)&sdst[cc * 4] = make_float4(skp[cc*4], skp[cc*4+1], skp[cc*4+2], skp[cc*4+3]);
    }
    __syncthreads();

    f32x4 acc[4][2];
    #pragma unroll
    for (int i = 0; i < 4; ++i)
        #pragma unroll
        for (int j = 0; j < 2; ++j) acc[i][j] = (f32x4)0.f;
    #pragma unroll
    for (int ks = 0; ks < 2; ++ks) {
        short8 a[4], b[2];
        #pragma unroll
        for (int mt = 0; mt < 4; ++mt)
            a[mt] = *(const short8*)&As[(wm + mt * 16 + r16) * 72 + ks * 32 + q * 8];
        #pragma unroll
        for (int nt = 0; nt < 2; ++nt)
            b[nt] = *(const short8*)&Bs[(wn + nt * 16 + r16) * 72 + ks * 32 + q * 8];
        #pragma unroll
        for (int mt = 0; mt < 4; ++mt)
            #pragma unroll
            for (int nt = 0; nt < 2; ++nt)
                acc[mt][nt] = __builtin_amdgcn_mfma_f32_16x16x32_bf16(a[mt], b[nt], acc[mt][nt], 0, 0, 0);
    }

    #pragma unroll
    for (int mt = 0; mt < 4; ++mt) {
        float sreg[4] = {0.f, 0.f, 0.f, 0.f};
        #pragma unroll
        for (int nt = 0; nt < 2; ++nt) {
            int n = wn + nt * 16 + r16;
            float bv = b2[kl * 64 + n];
            #pragma unroll
            for (int reg = 0; reg < 4; ++reg) {
                int lr = wm + mt * 16 + q * 4 + reg;
                float v = Sk[lr * 68 + n] + fmaxf(acc[mt][nt][reg] + bv, 0.f);
                xsum[(size_t)(bm + lr) * 2560 + kl * 64 + n] = v;
                sreg[reg] += v * v;
            }
        }
        // sum over the 16 lanes of the r16 group (cols of this wave-half)
        #pragma unroll
        for (int reg = 0; reg < 4; ++reg) {
            float s = sreg[reg];
            s += __shfl_xor(s, 1); s += __shfl_xor(s, 2);
            s += __shfl_xor(s, 4); s += __shfl_xor(s, 8);
            if (r16 == 0) {
                int row = bm + wm + mt * 16 + q * 4 + reg;
                part8[(size_t)row * 80 + kl * 2 + half] = s;
            }
        }
    }
}

// ---------------------------------------------------------------------------
// Norm-argmax + mask: norms from part8, first-max argmax, write xrec bf16.
// ---------------------------------------------------------------------------
__global__ __launch_bounds__(256) void mask_kernel(
    const float* __restrict__ xs, const float* __restrict__ part8,
    unsigned short* __restrict__ xrec)
{
    int b = blockIdx.x;
    int tid = threadIdx.x;
    __shared__ float norms[10];
    __shared__ int act_sh;
    if (tid < 10) {
        float s = 0.f;
        #pragma unroll
        for (int j = 0; j < 8; ++j) s += part8[(size_t)b * 80 + tid * 8 + j];
        norms[tid] = s;
    }
    __syncthreads();
    if (tid == 0) {
        int best = 0; float bn = -1.f;
        #pragma unroll
        for (int k = 0; k < 10; ++k)
            if (norms[k] > bn) { bn = norms[k]; best = k; }
        act_sh = best;
    }
    __syncthreads();
    int act = act_sh;
    const float* xb = xs + (size_t)b * 2560;
    unsigned short* xr = xrec + (size_t)b * 2560;
    #pragma unroll
    for (int k = 0; k < 10; ++k) {
        int idx = k * 256 + tid;
        xr[idx] = (k == act) ? f2bf(xb[idx]) : (unsigned short)0;
    }
}

// ---------------------------------------------------------------------------
// Split-K MFMA GEMM (m97 structure): P[z] = A[M,Kp] @ Bt[Np,Kp]^T slice
// 128x128 tile, BK=32, 4 waves (2x2), 4x4 frags of 16x16x32.
// ---------------------------------------------------------------------------
#define SPLITK 4
__global__ __launch_bounds__(256) void gemm_splitk(
    const unsigned short* __restrict__ A, int ldA,
    const unsigned short* __restrict__ Bt, int ldB,
    float* __restrict__ P, int Np, int kper)
{
    __shared__ __align__(16) unsigned short As[128 * 32];
    __shared__ __align__(16) unsigned short Bs[128 * 32];

    int tid = threadIdx.x;
    int bn = blockIdx.x * 128;
    int bm = blockIdx.y * 128;
    int kz = blockIdx.z * kper;

    int w = tid >> 6, lane = tid & 63;
    int wm = (w >> 1) * 64, wn = (w & 1) * 64;
    int q = lane >> 4, r16 = lane & 15;

    int srow = tid >> 2, skq = tid & 3;

    f32x4 acc[4][4];
    #pragma unroll
    for (int i = 0; i < 4; ++i)
        #pragma unroll
        for (int j = 0; j < 4; ++j) acc[i][j] = (f32x4)0.f;

    for (int kk = 0; kk < kper; kk += 32) {
        int k0 = kz + kk;
        const unsigned short* ga = A + (size_t)(bm + srow) * ldA + k0 + skq * 8;
        GLD16(ga, &As[tid * 8]);
        GLD16(ga + (size_t)64 * ldA, &As[(tid + 256) * 8]);
        const unsigned short* gb = Bt + (size_t)(bn + srow) * ldB + k0 + skq * 8;
        GLD16(gb, &Bs[tid * 8]);
        GLD16(gb + (size_t)64 * ldB, &Bs[(tid + 256) * 8]);
        __syncthreads();

        short8 a[4], b[4];
        #pragma unroll
        for (int mt = 0; mt < 4; ++mt)
            a[mt] = *(const short8*)&As[(wm + mt * 16 + r16) * 32 + q * 8];
        #pragma unroll
        for (int nt = 0; nt < 4; ++nt)
            b[nt] = *(const short8*)&Bs[(wn + nt * 16 + r16) * 32 + q * 8];
        #pragma unroll
        for (int mt = 0; mt < 4; ++mt)
            #pragma unroll
            for (int nt = 0; nt < 4; ++nt)
                acc[mt][nt] = __builtin_amdgcn_mfma_f32_16x16x32_bf16(a[mt], b[nt], acc[mt][nt], 0, 0, 0);
        __syncthreads();
    }

    float* Pz = P + (size_t)blockIdx.z * 512 * Np;
    #pragma unroll
    for (int mt = 0; mt < 4; ++mt) {
        #pragma unroll
        for (int nt = 0; nt < 4; ++nt) {
            int cn = bn + wn + nt * 16 + r16;
            #pragma unroll
            for (int reg = 0; reg < 4; ++reg) {
                int cm = bm + wm + mt * 16 + q * 4 + reg;
                Pz[(size_t)cm * Np + cn] = acc[mt][nt][reg];
            }
        }
    }
}

// ---------------------------------------------------------------------------
// Combine split-K partials + bias + act. MODE 0: relu->bf16. 1: sigmoid->f32.
// ---------------------------------------------------------------------------
template<int MODE>
__global__ __launch_bounds__(256) void combine_kernel(
    const float* __restrict__ P, const float* __restrict__ bias,
    void* __restrict__ out, int Np, int N_real)
{
    int gid = blockIdx.x * 256 + threadIdx.x;
    int n0 = (gid * 4) % Np;
    int m  = (gid * 4) / Np;
    size_t MN = (size_t)512 * Np;
    const float* p = P + (size_t)m * Np + n0;
    f32x4 s = *(const f32x4*)p;
    s += *(const f32x4*)(p + MN);
    s += *(const f32x4*)(p + 2 * MN);
    s += *(const f32x4*)(p + 3 * MN);
    f32x4 bv = (n0 < N_real) ? *(const f32x4*)(bias + n0) : (f32x4)0.f;
    s += bv;
    if (MODE == 0) {
        unsigned int lo = (unsigned int)f2bf(fmaxf(s[0], 0.f)) | ((unsigned int)f2bf(fmaxf(s[1], 0.f)) << 16);
        unsigned int hi = (unsigned int)f2bf(fmaxf(s[2], 0.f)) | ((unsigned int)f2bf(fmaxf(s[3], 0.f)) << 16);
        *(uint2*)((unsigned short*)out + (size_t)m * Np + n0) = make_uint2(lo, hi);
    } else {
        f32x4 v;
        v[0] = 1.f / (1.f + expf(-s[0]));
        v[1] = 1.f / (1.f + expf(-s[1]));
        v[2] = 1.f / (1.f + expf(-s[2]));
        v[3] = 1.f / (1.f + expf(-s[3]));
        *(f32x4*)((float*)out + (size_t)m * Np + n0) = v;
    }
}

extern "C" void kernel_launch(void* const* d_in, const int* in_sizes, int n_in,
                              void* d_out, int out_size, void* d_ws, size_t ws_size,
                              hipStream_t stream) {
    const float* x   = (const float*)d_in[0];
    const float* C1  = (const float*)d_in[1];
    const float* W1  = (const float*)d_in[2];
    const float* b1  = (const float*)d_in[3];
    const float* Cs  = (const float*)d_in[4];
    const float* C2  = (const float*)d_in[5];
    const float* W2  = (const float*)d_in[6];
    const float* b2  = (const float*)d_in[7];
    const float* Wr1 = (const float*)d_in[8];
    const float* br1 = (const float*)d_in[9];
    const float* Wr2 = (const float*)d_in[10];
    const float* br2 = (const float*)d_in[11];
    const float* Wr3 = (const float*)d_in[12];
    const float* br3 = (const float*)d_in[13];

    float* out = (float*)d_out;
    float* out0     = out;              // (512,3072) f32 sigmoid output
    float* xsum_out = out + OUT0_SZ;    // (512,2560) f32 x_sum

    // workspace layout (bytes)
    char* base = (char*)d_ws;
    unsigned short* xrec  = (unsigned short*)(base);              //   2,621,440
    unsigned short* h1    = (unsigned short*)(base +   2621440);  //   5,242,880
    unsigned short* h2    = (unsigned short*)(base +   7864320);  //   4,194,304
    unsigned short* Wt1   = (unsigned short*)(base +  12058624);  //  26,214,400
    unsigned short* Wt2   = (unsigned short*)(base +  38273024);  //  41,943,040
    unsigned short* Wt3   = (unsigned short*)(base +  80216064);  //  25,165,824
    float*          Pbuf  = (float*)(base + 105381888);           //  41,943,040
    unsigned short* xp    = (unsigned short*)(base + 147324928);  //   3,145,728
    unsigned short* W1t   = (unsigned short*)(base + 150470656);  //     393,216
    unsigned short* W2t   = (unsigned short*)(base + 150863872);  //     327,680
    float*          part8 = (float*)(base + 151191552);           //     163,840
    // total: 151,355,392 B

    // prep: all weight transposes, one dispatch
    convT_all<<<11480, 256, 0, stream>>>(Wr1, Wt1, Wr2, Wt2, Wr3, Wt3,
                                         W1, W1t, W2, W2t);

    // capsule path: pooled MFMA GEMMs (C is 0/1 -> sparse pooling)
    caps_gemm1<<<dim3(48, 4), 256, 0, stream>>>(x, C1, W1t, b1, xp);
    caps_gemm2<<<dim3(40, 4), 256, 0, stream>>>(xp, Cs, C2, W2t, b2, xsum_out, part8);
    mask_kernel<<<BATCH, 256, 0, stream>>>(xsum_out, part8, xrec);

    // --- MLP layer 1: (512,2560) @ (2560,5000) -> h1 (512,5120 bf16) ---
    gemm_splitk<<<dim3(5120 / 128, 4, SPLITK), 256, 0, stream>>>(xrec, 2560, Wt1, 2560, Pbuf, 5120, 2560 / SPLITK);
    combine_kernel<0><<<512 * 5120 / 1024, 256, 0, stream>>>(Pbuf, br1, h1, 5120, 5000);

    // --- MLP layer 2: (512,5120) @ (5120,4000) -> h2 (512,4096 bf16) ---
    gemm_splitk<<<dim3(4096 / 128, 4, SPLITK), 256, 0, stream>>>(h1, 5120, Wt2, 5120, Pbuf, 4096, 5120 / SPLITK);
    combine_kernel<0><<<512 * 4096 / 1024, 256, 0, stream>>>(Pbuf, br2, h2, 4096, 4000);

    // --- MLP layer 3: (512,4096) @ (4096,3072) -> out0 (512,3072 f32) ---
    gemm_splitk<<<dim3(3072 / 128, 4, SPLITK), 256, 0, stream>>>(h2, 4096, Wt3, 4096, Pbuf, 3072, 4096 / SPLITK);
    combine_kernel<1><<<512 * 3072 / 1024, 256, 0, stream>>>(Pbuf, br3, out0, 3072, 3072);
}

// Round 7
// 409.754 us; speedup vs baseline: 1.1651x; 1.0006x over previous
//
#include <hip/hip_runtime.h>
#include <math.h>

// B=512, IN_CORES=12, N_PRIM=12, N_PAR=10, RFPC=4, RF=64, CAP=256
// out = concat( sigmoid MLP output (512,3072) f32 , x_sum (512,2560) f32 )
// C1/C_skip/C2 are Bernoulli 0/1 -> routing einsum is sparse sum-pooling.

#define BATCH 512
#define OUT0_SZ (512*3072)

typedef __attribute__((ext_vector_type(8))) short short8;   // 8 x bf16
typedef __attribute__((ext_vector_type(4))) float f32x4;

__device__ inline unsigned short f2bf(float f) {
    union { float f; unsigned u; } v; v.f = f;
    unsigned r = v.u + 0x7fffu + ((v.u >> 16) & 1u);   // RNE
    return (unsigned short)(r >> 16);
}
__device__ inline float bf2f(unsigned int hi16) {       // low 16 bits = bf16
    union { unsigned u; float f; } v; v.u = hi16 << 16; return v.f;
}

// async global->LDS, 16 bytes per lane
#define GLD16(g, l) __builtin_amdgcn_global_load_lds( \
    (const __attribute__((address_space(1))) unsigned int*)(g), \
    (__attribute__((address_space(3))) unsigned int*)(l), 16, 0, 0)

// ---------------------------------------------------------------------------
// Prep: MLP weight convert+transpose (f32 [K][N] -> bf16 [N][K], padded)
// + capsule weight transpose W1/W2 (per-kl 64x64, [m][n] -> [n][m] bf16).
// 64x64 LDS tiles, stride 65. One dispatch, flattened grid.
//   L1 40x80=3200 | L2 80x64=5120 | L3 64x48=3072 | W1t 48 | W2t 40
// ---------------------------------------------------------------------------
__global__ __launch_bounds__(256) void convT_all(
    const float* __restrict__ Wr1, unsigned short* __restrict__ Wt1,
    const float* __restrict__ Wr2, unsigned short* __restrict__ Wt2,
    const float* __restrict__ Wr3, unsigned short* __restrict__ Wt3,
    const float* __restrict__ W1,  unsigned short* __restrict__ W1t,
    const float* __restrict__ W2,  unsigned short* __restrict__ W2t)
{
    __shared__ float t[64 * 65];
    int bid = blockIdx.x;
    const float* W; unsigned short* Wt;
    int Kr, Nr, Kp, ktiles, rem;
    if (bid < 3200)       { W = Wr1; Wt = Wt1; Kr = 2560; Nr = 5000; Kp = 2560; ktiles = 40; rem = bid; }
    else if (bid < 8320)  { W = Wr2; Wt = Wt2; Kr = 5000; Nr = 4000; Kp = 5120; ktiles = 80; rem = bid - 3200; }
    else if (bid < 11392) { W = Wr3; Wt = Wt3; Kr = 4000; Nr = 3072; Kp = 4096; ktiles = 64; rem = bid - 8320; }
    else if (bid < 11440) { int kl = bid - 11392; W = W1 + (size_t)kl * 4096; Wt = W1t + (size_t)kl * 4096;
                            Kr = 64; Nr = 64; Kp = 64; ktiles = 1; rem = 0; }
    else                  { int kl = bid - 11440; W = W2 + (size_t)kl * 4096; Wt = W2t + (size_t)kl * 4096;
                            Kr = 64; Nr = 64; Kp = 64; ktiles = 1; rem = 0; }
    int k0 = (rem % ktiles) * 64;
    int n0 = (rem / ktiles) * 64;
    int tid = threadIdx.x;

    // load: float4 global -> scalar LDS (stride 65 -> 2-way banking, free)
    {
        int kr = tid >> 4;
        int nc = (tid & 15) * 4;
        #pragma unroll
        for (int p = 0; p < 4; ++p) {
            int k = k0 + kr + p * 16;
            float4 v = make_float4(0.f, 0.f, 0.f, 0.f);
            if (k < Kr) {
                if (n0 + nc + 3 < Nr) {
                    v = *(const float4*)&W[(size_t)k * Nr + n0 + nc];
                } else {
                    float tmp[4] = {0.f, 0.f, 0.f, 0.f};
                    #pragma unroll
                    for (int j = 0; j < 4; ++j)
                        if (n0 + nc + j < Nr) tmp[j] = W[(size_t)k * Nr + n0 + nc + j];
                    v = make_float4(tmp[0], tmp[1], tmp[2], tmp[3]);
                }
            }
            float* row = &t[(kr + p * 16) * 65 + nc];
            row[0] = v.x; row[1] = v.y; row[2] = v.z; row[3] = v.w;
        }
    }
    __syncthreads();
    // store: strided LDS reads (2-way), pack bf16, two 16B stores
    {
        int nr = tid >> 2;
        int kc = (tid & 3) * 16;
        unsigned int u[8];
        #pragma unroll
        for (int j = 0; j < 8; ++j) {
            float v0 = t[(kc + 2 * j)     * 65 + nr];
            float v1 = t[(kc + 2 * j + 1) * 65 + nr];
            u[j] = (unsigned int)f2bf(v0) | ((unsigned int)f2bf(v1) << 16);
        }
        unsigned int* dst = (unsigned int*)&Wt[(size_t)(n0 + nr) * Kp + k0 + kc];
        *(uint4*)(dst)     = make_uint4(u[0], u[1], u[2], u[3]);
        *(uint4*)(dst + 4) = make_uint4(u[4], u[5], u[6], u[7]);
    }
}

// ---------------------------------------------------------------------------
// Capsule layer 1 as pooled MFMA GEMM. Grid (48 kl, 4 m-tiles), 256 thr.
// ---------------------------------------------------------------------------
__global__ __launch_bounds__(256) void caps_gemm1(
    const float* __restrict__ x, const float* __restrict__ C1,
    const unsigned short* __restrict__ W1t, const float* __restrict__ b1,
    unsigned short* __restrict__ xp)
{
    __shared__ __align__(16) unsigned short As[128 * 72];
    __shared__ __align__(16) unsigned short Bs[64 * 72];
    __shared__ float Csh[48];
    int kl = blockIdx.x;
    int bm = blockIdx.y * 128;
    int tid = threadIdx.x;
    int w = tid >> 6, lane = tid & 63, q = lane >> 4, r16 = lane & 15;
    int wm = (w >> 1) * 64, wn = (w & 1) * 32;

    if (tid < 48) Csh[tid] = C1[tid * 48 + kl];
    {   // stage B = W1t[kl], 64x64 bf16, padded stride 72
        const uint4* src = (const uint4*)(W1t + (size_t)kl * 4096);
        #pragma unroll
        for (int p = 0; p < 2; ++p) {
            int c = tid + p * 256;
            int row = c >> 3, cq = c & 7;
            *(uint4*)&Bs[row * 72 + cq * 8] = src[c];
        }
    }
    __syncthreads();

    // A-pool: thread -> (row = tid>>1, 32-col half)
    int arow = tid >> 1, ah = (tid & 1) * 32;
    float accp[32];
    #pragma unroll
    for (int i = 0; i < 32; ++i) accp[i] = 0.f;
    const float* xrow = x + (size_t)(bm + arow) * 3072 + ah;
    for (int ij = 0; ij < 48; ++ij) {
        float c = Csh[ij];
        if (c != 0.f) {
            const float4* p4 = (const float4*)(xrow + ij * 64);
            #pragma unroll
            for (int cc = 0; cc < 8; ++cc) {
                float4 v = p4[cc];
                accp[cc * 4 + 0] = fmaf(c, v.x, accp[cc * 4 + 0]);
                accp[cc * 4 + 1] = fmaf(c, v.y, accp[cc * 4 + 1]);
                accp[cc * 4 + 2] = fmaf(c, v.z, accp[cc * 4 + 2]);
                accp[cc * 4 + 3] = fmaf(c, v.w, accp[cc * 4 + 3]);
            }
        }
    }
    {   // pack -> As
        unsigned short* dst = &As[arow * 72 + ah];
        #pragma unroll
        for (int cc = 0; cc < 4; ++cc) {
            unsigned int u[4];
            #pragma unroll
            for (int j = 0; j < 4; ++j)
                u[j] = (unsigned int)f2bf(accp[cc * 8 + 2 * j]) |
                       ((unsigned int)f2bf(accp[cc * 8 + 2 * j + 1]) << 16);
            *(uint4*)&dst[cc * 8] = make_uint4(u[0], u[1], u[2], u[3]);
        }
    }
    __syncthreads();

    f32x4 acc[4][2];
    #pragma unroll
    for (int i = 0; i < 4; ++i)
        #pragma unroll
        for (int j = 0; j < 2; ++j) acc[i][j] = (f32x4)0.f;
    #pragma unroll
    for (int ks = 0; ks < 2; ++ks) {
        short8 a[4], b[2];
        #pragma unroll
        for (int mt = 0; mt < 4; ++mt)
            a[mt] = *(const short8*)&As[(wm + mt * 16 + r16) * 72 + ks * 32 + q * 8];
        #pragma unroll
        for (int nt = 0; nt < 2; ++nt)
            b[nt] = *(const short8*)&Bs[(wn + nt * 16 + r16) * 72 + ks * 32 + q * 8];
        #pragma unroll
        for (int mt = 0; mt < 4; ++mt)
            #pragma unroll
            for (int nt = 0; nt < 2; ++nt)
                acc[mt][nt] = __builtin_amdgcn_mfma_f32_16x16x32_bf16(a[mt], b[nt], acc[mt][nt], 0, 0, 0);
    }

    #pragma unroll
    for (int mt = 0; mt < 4; ++mt) {
        #pragma unroll
        for (int nt = 0; nt < 2; ++nt) {
            int n = wn + nt * 16 + r16;
            float bv = b1[kl * 64 + n];
            #pragma unroll
            for (int reg = 0; reg < 4; ++reg) {
                int row = bm + wm + mt * 16 + q * 4 + reg;
                xp[(size_t)row * 3072 + kl * 64 + n] = f2bf(fmaxf(acc[mt][nt][reg] + bv, 0.f));
            }
        }
    }
}

// ---------------------------------------------------------------------------
// Capsule layer 2 + skip + norms. Grid (40 kl, 4 m-tiles), 256 thr.
// ---------------------------------------------------------------------------
__global__ __launch_bounds__(256) void caps_gemm2(
    const unsigned short* __restrict__ xp, const float* __restrict__ Cs,
    const float* __restrict__ C2, const unsigned short* __restrict__ W2t,
    const float* __restrict__ b2, float* __restrict__ xsum,
    float* __restrict__ part8)
{
    __shared__ __align__(16) unsigned short As[128 * 72];
    __shared__ __align__(16) unsigned short Bs[64 * 72];
    __shared__ __align__(16) float Sk[128 * 68];
    __shared__ float C2sh[48], Cssh[48];
    int kl = blockIdx.x;
    int bm = blockIdx.y * 128;
    int tid = threadIdx.x;
    int w = tid >> 6, lane = tid & 63, q = lane >> 4, r16 = lane & 15;
    int wm = (w >> 1) * 64, wn = (w & 1) * 32;
    int half = w & 1;

    if (tid < 48) { C2sh[tid] = C2[tid * 40 + kl]; Cssh[tid] = Cs[tid * 40 + kl]; }
    {
        const uint4* src = (const uint4*)(W2t + (size_t)kl * 4096);
        #pragma unroll
        for (int p = 0; p < 2; ++p) {
            int c = tid + p * 256;
            int row = c >> 3, cq = c & 7;
            *(uint4*)&Bs[row * 72 + cq * 8] = src[c];
        }
    }
    __syncthreads();

    int arow = tid >> 1, ah = (tid & 1) * 32;
    float accp[32], skp[32];
    #pragma unroll
    for (int i = 0; i < 32; ++i) { accp[i] = 0.f; skp[i] = 0.f; }
    const unsigned short* xprow = xp + (size_t)(bm + arow) * 3072 + ah;
    for (int ij = 0; ij < 48; ++ij) {
        float c2 = C2sh[ij], cs = Cssh[ij];
        if (c2 != 0.f || cs != 0.f) {
            const uint4* p4 = (const uint4*)(xprow + ij * 64);
            #pragma unroll
            for (int cc = 0; cc < 4; ++cc) {
                uint4 v = p4[cc];
                unsigned int uu[4] = {v.x, v.y, v.z, v.w};
                #pragma unroll
                for (int j = 0; j < 4; ++j) {
                    float lo = bf2f(uu[j] & 0xffffu);
                    float hi = bf2f(uu[j] >> 16);
                    int idx = cc * 8 + 2 * j;
                    accp[idx]     = fmaf(c2, lo, accp[idx]);
                    accp[idx + 1] = fmaf(c2, hi, accp[idx + 1]);
                    skp[idx]      = fmaf(cs, lo, skp[idx]);
                    skp[idx + 1]  = fmaf(cs, hi, skp[idx + 1]);
                }
            }
        }
    }
    {
        unsigned short* dst = &As[arow * 72 + ah];
        #pragma unroll
        for (int cc = 0; cc < 4; ++cc) {
            unsigned int u[4];
            #pragma unroll
            for (int j = 0; j < 4; ++j)
                u[j] = (unsigned int)f2bf(accp[cc * 8 + 2 * j]) |
                       ((unsigned int)f2bf(accp[cc * 8 + 2 * j + 1]) << 16);
            *(uint4*)&dst[cc * 8] = make_uint4(u[0], u[1], u[2], u[3]);
        }
        float* sdst = &Sk[arow * 68 + ah];
        #pragma unroll
        for (int cc = 0; cc < 8; ++cc)
            *(float4*)&sdst[cc * 4] = make_float4(skp[cc*4], skp[cc*4+1], skp[cc*4+2], skp[cc*4+3]);
    }
    __syncthreads();

    f32x4 acc[4][2];
    #pragma unroll
    for (int i = 0; i < 4; ++i)
        #pragma unroll
        for (int j = 0; j < 2; ++j) acc[i][j] = (f32x4)0.f;
    #pragma unroll
    for (int ks = 0; ks < 2; ++ks) {
        short8 a[4], b[2];
        #pragma unroll
        for (int mt = 0; mt < 4; ++mt)
            a[mt] = *(const short8*)&As[(wm + mt * 16 + r16) * 72 + ks * 32 + q * 8];
        #pragma unroll
        for (int nt = 0; nt < 2; ++nt)
            b[nt] = *(const short8*)&Bs[(wn + nt * 16 + r16) * 72 + ks * 32 + q * 8];
        #pragma unroll
        for (int mt = 0; mt < 4; ++mt)
            #pragma unroll
            for (int nt = 0; nt < 2; ++nt)
                acc[mt][nt] = __builtin_amdgcn_mfma_f32_16x16x32_bf16(a[mt], b[nt], acc[mt][nt], 0, 0, 0);
    }

    #pragma unroll
    for (int mt = 0; mt < 4; ++mt) {
        float sreg[4] = {0.f, 0.f, 0.f, 0.f};
        #pragma unroll
        for (int nt = 0; nt < 2; ++nt) {
            int n = wn + nt * 16 + r16;
            float bv = b2[kl * 64 + n];
            #pragma unroll
            for (int reg = 0; reg < 4; ++reg) {
                int lr = wm + mt * 16 + q * 4 + reg;
                float v = Sk[lr * 68 + n] + fmaxf(acc[mt][nt][reg] + bv, 0.f);
                xsum[(size_t)(bm + lr) * 2560 + kl * 64 + n] = v;
                sreg[reg] += v * v;
            }
        }
        #pragma unroll
        for (int reg = 0; reg < 4; ++reg) {
            float s = sreg[reg];
            s += __shfl_xor(s, 1); s += __shfl_xor(s, 2);
            s += __shfl_xor(s, 4); s += __shfl_xor(s, 8);
            if (r16 == 0) {
                int row = bm + wm + mt * 16 + q * 4 + reg;
                part8[(size_t)row * 80 + kl * 2 + half] = s;
            }
        }
    }
}

// ---------------------------------------------------------------------------
// Norm-argmax + mask: norms from part8, first-max argmax, write xrec bf16.
// ---------------------------------------------------------------------------
__global__ __launch_bounds__(256) void mask_kernel(
    const float* __restrict__ xs, const float* __restrict__ part8,
    unsigned short* __restrict__ xrec)
{
    int b = blockIdx.x;
    int tid = threadIdx.x;
    __shared__ float norms[10];
    __shared__ int act_sh;
    if (tid < 10) {
        float s = 0.f;
        #pragma unroll
        for (int j = 0; j < 8; ++j) s += part8[(size_t)b * 80 + tid * 8 + j];
        norms[tid] = s;
    }
    __syncthreads();
    if (tid == 0) {
        int best = 0; float bn = -1.f;
        #pragma unroll
        for (int k = 0; k < 10; ++k)
            if (norms[k] > bn) { bn = norms[k]; best = k; }
        act_sh = best;
    }
    __syncthreads();
    int act = act_sh;
    const float* xb = xs + (size_t)b * 2560;
    unsigned short* xr = xrec + (size_t)b * 2560;
    #pragma unroll
    for (int k = 0; k < 10; ++k) {
        int idx = k * 256 + tid;
        xr[idx] = (k == act) ? f2bf(xb[idx]) : (unsigned short)0;
    }
}

// ---------------------------------------------------------------------------
// Split-K MFMA GEMM, 64(M)x128(N) tile, BK=32. 256 thr = 4 waves (2x2),
// each wave 32m x 64n = 2x4 frags of 16x16x32. Grid (Np/128, M/64, SPLITK)
// -> 3-5 blocks/CU co-resident (fixes the barrier-drain starvation of the
// 128x128 version: grid was 1.5-2.5/CU, m114 overlap needs ~3+).
// ---------------------------------------------------------------------------
#define SPLITK 4
__global__ __launch_bounds__(256) void gemm_splitk(
    const unsigned short* __restrict__ A, int ldA,
    const unsigned short* __restrict__ Bt, int ldB,
    float* __restrict__ P, int Np, int kper)
{
    __shared__ __align__(16) unsigned short As[64 * 32];
    __shared__ __align__(16) unsigned short Bs[128 * 32];

    int tid = threadIdx.x;
    int bn = blockIdx.x * 128;
    int bm = blockIdx.y * 64;
    int kz = blockIdx.z * kper;

    int w = tid >> 6, lane = tid & 63;
    int wm = (w >> 1) * 32, wn = (w & 1) * 64;
    int q = lane >> 4, r16 = lane & 15;

    int srow = tid >> 2, skq = tid & 3;   // staging chunk -> (row, 16B quarter)

    f32x4 acc[2][4];
    #pragma unroll
    for (int i = 0; i < 2; ++i)
        #pragma unroll
        for (int j = 0; j < 4; ++j) acc[i][j] = (f32x4)0.f;

    for (int kk = 0; kk < kper; kk += 32) {
        int k0 = kz + kk;
        const unsigned short* ga = A + (size_t)(bm + srow) * ldA + k0 + skq * 8;
        GLD16(ga, &As[tid * 8]);
        const unsigned short* gb = Bt + (size_t)(bn + srow) * ldB + k0 + skq * 8;
        GLD16(gb, &Bs[tid * 8]);
        GLD16(gb + (size_t)64 * ldB, &Bs[(tid + 256) * 8]);
        __syncthreads();

        short8 a[2], b[4];
        #pragma unroll
        for (int mt = 0; mt < 2; ++mt)
            a[mt] = *(const short8*)&As[(wm + mt * 16 + r16) * 32 + q * 8];
        #pragma unroll
        for (int nt = 0; nt < 4; ++nt)
            b[nt] = *(const short8*)&Bs[(wn + nt * 16 + r16) * 32 + q * 8];
        #pragma unroll
        for (int mt = 0; mt < 2; ++mt)
            #pragma unroll
            for (int nt = 0; nt < 4; ++nt)
                acc[mt][nt] = __builtin_amdgcn_mfma_f32_16x16x32_bf16(a[mt], b[nt], acc[mt][nt], 0, 0, 0);
        __syncthreads();
    }

    float* Pz = P + (size_t)blockIdx.z * 512 * Np;
    #pragma unroll
    for (int mt = 0; mt < 2; ++mt) {
        #pragma unroll
        for (int nt = 0; nt < 4; ++nt) {
            int cn = bn + wn + nt * 16 + r16;
            #pragma unroll
            for (int reg = 0; reg < 4; ++reg) {
                int cm = bm + wm + mt * 16 + q * 4 + reg;
                Pz[(size_t)cm * Np + cn] = acc[mt][nt][reg];
            }
        }
    }
}

// ---------------------------------------------------------------------------
// Combine split-K partials + bias + act. MODE 0: relu->bf16. 1: sigmoid->f32.
// ---------------------------------------------------------------------------
template<int MODE>
__global__ __launch_bounds__(256) void combine_kernel(
    const float* __restrict__ P, const float* __restrict__ bias,
    void* __restrict__ out, int Np, int N_real)
{
    int gid = blockIdx.x * 256 + threadIdx.x;
    int n0 = (gid * 4) % Np;
    int m  = (gid * 4) / Np;
    size_t MN = (size_t)512 * Np;
    const float* p = P + (size_t)m * Np + n0;
    f32x4 s = *(const f32x4*)p;
    s += *(const f32x4*)(p + MN);
    s += *(const f32x4*)(p + 2 * MN);
    s += *(const f32x4*)(p + 3 * MN);
    f32x4 bv = (n0 < N_real) ? *(const f32x4*)(bias + n0) : (f32x4)0.f;
    s += bv;
    if (MODE == 0) {
        unsigned int lo = (unsigned int)f2bf(fmaxf(s[0], 0.f)) | ((unsigned int)f2bf(fmaxf(s[1], 0.f)) << 16);
        unsigned int hi = (unsigned int)f2bf(fmaxf(s[2], 0.f)) | ((unsigned int)f2bf(fmaxf(s[3], 0.f)) << 16);
        *(uint2*)((unsigned short*)out + (size_t)m * Np + n0) = make_uint2(lo, hi);
    } else {
        f32x4 v;
        v[0] = 1.f / (1.f + expf(-s[0]));
        v[1] = 1.f / (1.f + expf(-s[1]));
        v[2] = 1.f / (1.f + expf(-s[2]));
        v[3] = 1.f / (1.f + expf(-s[3]));
        *(f32x4*)((float*)out + (size_t)m * Np + n0) = v;
    }
}

extern "C" void kernel_launch(void* const* d_in, const int* in_sizes, int n_in,
                              void* d_out, int out_size, void* d_ws, size_t ws_size,
                              hipStream_t stream) {
    const float* x   = (const float*)d_in[0];
    const float* C1  = (const float*)d_in[1];
    const float* W1  = (const float*)d_in[2];
    const float* b1  = (const float*)d_in[3];
    const float* Cs  = (const float*)d_in[4];
    const float* C2  = (const float*)d_in[5];
    const float* W2  = (const float*)d_in[6];
    const float* b2  = (const float*)d_in[7];
    const float* Wr1 = (const float*)d_in[8];
    const float* br1 = (const float*)d_in[9];
    const float* Wr2 = (const float*)d_in[10];
    const float* br2 = (const float*)d_in[11];
    const float* Wr3 = (const float*)d_in[12];
    const float* br3 = (const float*)d_in[13];

    float* out = (float*)d_out;
    float* out0     = out;              // (512,3072) f32 sigmoid output
    float* xsum_out = out + OUT0_SZ;    // (512,2560) f32 x_sum

    // workspace layout (bytes)
    char* base = (char*)d_ws;
    unsigned short* xrec  = (unsigned short*)(base);              //   2,621,440
    unsigned short* h1    = (unsigned short*)(base +   2621440);  //   5,242,880
    unsigned short* h2    = (unsigned short*)(base +   7864320);  //   4,194,304
    unsigned short* Wt1   = (unsigned short*)(base +  12058624);  //  26,214,400
    unsigned short* Wt2   = (unsigned short*)(base +  38273024);  //  41,943,040
    unsigned short* Wt3   = (unsigned short*)(base +  80216064);  //  25,165,824
    float*          Pbuf  = (float*)(base + 105381888);           //  41,943,040
    unsigned short* xp    = (unsigned short*)(base + 147324928);  //   3,145,728
    unsigned short* W1t   = (unsigned short*)(base + 150470656);  //     393,216
    unsigned short* W2t   = (unsigned short*)(base + 150863872);  //     327,680
    float*          part8 = (float*)(base + 151191552);           //     163,840
    // total: 151,355,392 B

    // prep: all weight transposes, one dispatch
    convT_all<<<11480, 256, 0, stream>>>(Wr1, Wt1, Wr2, Wt2, Wr3, Wt3,
                                         W1, W1t, W2, W2t);

    // capsule path: pooled MFMA GEMMs (C is 0/1 -> sparse pooling)
    caps_gemm1<<<dim3(48, 4), 256, 0, stream>>>(x, C1, W1t, b1, xp);
    caps_gemm2<<<dim3(40, 4), 256, 0, stream>>>(xp, Cs, C2, W2t, b2, xsum_out, part8);
    mask_kernel<<<BATCH, 256, 0, stream>>>(xsum_out, part8, xrec);

    // --- MLP layer 1: (512,2560) @ (2560,5000) -> h1 (512,5120 bf16) ---
    gemm_splitk<<<dim3(5120 / 128, 8, SPLITK), 256, 0, stream>>>(xrec, 2560, Wt1, 2560, Pbuf, 5120, 2560 / SPLITK);
    combine_kernel<0><<<512 * 5120 / 1024, 256, 0, stream>>>(Pbuf, br1, h1, 5120, 5000);

    // --- MLP layer 2: (512,5120) @ (5120,4000) -> h2 (512,4096 bf16) ---
    gemm_splitk<<<dim3(4096 / 128, 8, SPLITK), 256, 0, stream>>>(h1, 5120, Wt2, 5120, Pbuf, 4096, 5120 / SPLITK);
    combine_kernel<0><<<512 * 4096 / 1024, 256, 0, stream>>>(Pbuf, br2, h2, 4096, 4000);

    // --- MLP layer 3: (512,4096) @ (4096,3072) -> out0 (512,3072 f32) ---
    gemm_splitk<<<dim3(3072 / 128, 8, SPLITK), 256, 0, stream>>>(h2, 4096, Wt3, 4096, Pbuf, 3072, 4096 / SPLITK);
    combine_kernel<1><<<512 * 3072 / 1024, 256, 0, stream>>>(Pbuf, br3, out0, 3072, 3072);
}